// Round 3
// baseline (454.619 us; speedup 1.0000x reference)
//
#include <hip/hip_runtime.h>
#include <hip/hip_bf16.h>

typedef float f32x4  __attribute__((ext_vector_type(4)));
typedef float f32x16 __attribute__((ext_vector_type(16)));
typedef short bf16x8 __attribute__((ext_vector_type(8)));
typedef unsigned short u16x4 __attribute__((ext_vector_type(4)));
typedef unsigned short u16x8 __attribute__((ext_vector_type(8)));

__device__ inline unsigned short f2bf(float v) {
    __hip_bfloat16 h = __float2bfloat16(v);
    return *reinterpret_cast<unsigned short*>(&h);
}
__device__ inline float bf2f(unsigned short u) {
    __hip_bfloat16 h;
    *reinterpret_cast<unsigned short*>(&h) = u;
    return __bfloat162float(h);
}

// ---------------------------------------------------------------------------
// convert_split: fp32 -> bf16 hi + lo (elementwise), float4-vectorized
// ---------------------------------------------------------------------------
__global__ __launch_bounds__(256)
void convert_split(const float* __restrict__ X, unsigned short* __restrict__ H,
                   unsigned short* __restrict__ L, long n4)
{
    long i = (long)blockIdx.x * 256 + threadIdx.x;
    if (i >= n4) return;
    f32x4 v = ((const f32x4*)X)[i];
    u16x4 h, l;
#pragma unroll
    for (int k = 0; k < 4; ++k) {
        h[k] = f2bf(v[k]);
        l[k] = f2bf(v[k] - bf2f(h[k]));
    }
    ((u16x4*)H)[i] = h;
    ((u16x4*)L)[i] = l;
}

// ---------------------------------------------------------------------------
// transpose_w: W [D][D] fp32 row-major -> Wt [n][k] bf16 hi (+lo if SPL)
// ---------------------------------------------------------------------------
template<bool SPL>
__global__ __launch_bounds__(256)
void transpose_w(const float* __restrict__ W, unsigned short* __restrict__ Th,
                 unsigned short* __restrict__ Tl, int D)
{
    __shared__ float t[32][33];
    const int tid = threadIdx.x;
    const int bx = blockIdx.x * 32, by = blockIdx.y * 32;
    const int c = tid & 31, r0 = tid >> 5;
#pragma unroll
    for (int r = r0; r < 32; r += 8)
        t[r][c] = W[(long)(by + r) * D + bx + c];
    __syncthreads();
#pragma unroll
    for (int r = r0; r < 32; r += 8) {
        float v = t[c][r];                       // = W[by+c][bx+r]
        unsigned short h = f2bf(v);
        Th[(long)(bx + r) * D + by + c] = h;     // Wt[n=bx+r][k=by+c]
        if (SPL) Tl[(long)(bx + r) * D + by + c] = f2bf(v - bf2f(h));
    }
}

// ---------------------------------------------------------------------------
// gemm2: C = A @ B^T_layout (+bias). A bf16 [M][K] row-major (hi, + lo if SPLIT),
// B bf16 [N][K] row-major (hi, + lo). 128x128 tile, TK=32, 32x32x16 MFMA,
// global_load_lds width-16 staging.
// MODE: 0 plain; 1 causal tile skip (ct>rt); 2 K-loop bounded at (rt+1)*128.
// OUT:  0 fp32 Cf[ldc]; 1 split bf16 Ch/Cl[ldc]; 2 transposed bf16 Ch[b][col][s]
//       (via LDS, coalesced 16B stores).
// bias: col < nsplit -> bias[col], else bias2[col-nsplit]  (merged QK biases).
// ---------------------------------------------------------------------------
constexpr int TM = 128, TN = 128, TK = 32;

template<bool SPLIT, int MODE, int OUT>
__global__ __launch_bounds__(256)
void gemm2(const unsigned short* __restrict__ Ah, const unsigned short* __restrict__ Al,
           long sA, int lda,
           const unsigned short* __restrict__ Bh, const unsigned short* __restrict__ Bl,
           long sB, int ldb,
           float* __restrict__ Cf, unsigned short* __restrict__ Ch, unsigned short* __restrict__ Cl,
           long sC, int ldc, int K,
           const float* __restrict__ bias, const float* __restrict__ bias2, int nsplit,
           int batchS)
{
    const int rt = blockIdx.y, ct = blockIdx.x, bz = blockIdx.z;
    if (MODE == 1 && ct > rt) return;

    const unsigned short* gAh = Ah + (long)bz * sA;
    const unsigned short* gAl = SPLIT ? Al + (long)bz * sA : nullptr;
    const unsigned short* gBh = Bh + (long)bz * sB;
    const unsigned short* gBl = SPLIT ? Bl + (long)bz * sB : nullptr;

    const int row0 = rt * TM, col0 = ct * TN;
    const int k_end = (MODE == 2) ? min(K, (rt + 1) * TM) : K;

    __shared__ unsigned short sAh[TM * TK];               // 8 KB, 64 B rows, unpadded
    __shared__ unsigned short sBh[TN * TK];
    __shared__ unsigned short sAl[SPLIT ? TM * TK : 8];
    __shared__ unsigned short sBl[SPLIT ? TN * TK : 8];
    __shared__ unsigned short sVt[OUT == 2 ? TM * TN : 8]; // 32 KB transpose staging

    const int tid = threadIdx.x;
    const int lane = tid & 63, wave = tid >> 6;
    const int l32 = lane & 31, khalf = lane >> 5;
    const int wm = (wave >> 1) * 64, wn = (wave & 1) * 64;

    f32x16 acc[2][2] = {};

    for (int k0 = 0; k0 < k_end; k0 += TK) {
        // stage 128x32 bf16 tiles: 2 rounds of 256 lanes x 16 B each
#pragma unroll
        for (int rnd = 0; rnd < 2; ++rnd) {
            const int row = rnd * 64 + (tid >> 2);
            const long gA = (long)(row0 + row) * lda + k0 + (tid & 3) * 8;
            const long gB = (long)(col0 + row) * ldb + k0 + (tid & 3) * 8;
            const int lofs = rnd * 2048 + tid * 8;
            __builtin_amdgcn_global_load_lds(
                (const __attribute__((address_space(1))) void*)(gAh + gA),
                (__attribute__((address_space(3))) void*)(sAh + lofs), 16, 0, 0);
            __builtin_amdgcn_global_load_lds(
                (const __attribute__((address_space(1))) void*)(gBh + gB),
                (__attribute__((address_space(3))) void*)(sBh + lofs), 16, 0, 0);
            if (SPLIT) {
                __builtin_amdgcn_global_load_lds(
                    (const __attribute__((address_space(1))) void*)(gAl + gA),
                    (__attribute__((address_space(3))) void*)(sAl + lofs), 16, 0, 0);
                __builtin_amdgcn_global_load_lds(
                    (const __attribute__((address_space(1))) void*)(gBl + gB),
                    (__attribute__((address_space(3))) void*)(sBl + lofs), 16, 0, 0);
            }
        }
        __syncthreads();

        // fragments (32x32x16): A[m=l32][k=khalf*8+j], B[n=l32][k=khalf*8+j]
#pragma unroll
        for (int ks = 0; ks < 2; ++ks) {
            bf16x8 a_h[2], b_h[2];
#pragma unroll
            for (int fi = 0; fi < 2; ++fi)
                a_h[fi] = *(const bf16x8*)&sAh[(wm + fi * 32 + l32) * TK + ks * 16 + khalf * 8];
#pragma unroll
            for (int fj = 0; fj < 2; ++fj)
                b_h[fj] = *(const bf16x8*)&sBh[(wn + fj * 32 + l32) * TK + ks * 16 + khalf * 8];
            if (SPLIT) {
                bf16x8 a_l[2], b_l[2];
#pragma unroll
                for (int fi = 0; fi < 2; ++fi)
                    a_l[fi] = *(const bf16x8*)&sAl[(wm + fi * 32 + l32) * TK + ks * 16 + khalf * 8];
#pragma unroll
                for (int fj = 0; fj < 2; ++fj)
                    b_l[fj] = *(const bf16x8*)&sBl[(wn + fj * 32 + l32) * TK + ks * 16 + khalf * 8];
#pragma unroll
                for (int fi = 0; fi < 2; ++fi)
#pragma unroll
                    for (int fj = 0; fj < 2; ++fj) {
                        acc[fi][fj] = __builtin_amdgcn_mfma_f32_32x32x16_bf16(a_h[fi], b_h[fj], acc[fi][fj], 0, 0, 0);
                        acc[fi][fj] = __builtin_amdgcn_mfma_f32_32x32x16_bf16(a_h[fi], b_l[fj], acc[fi][fj], 0, 0, 0);
                        acc[fi][fj] = __builtin_amdgcn_mfma_f32_32x32x16_bf16(a_l[fi], b_h[fj], acc[fi][fj], 0, 0, 0);
                    }
            } else {
#pragma unroll
                for (int fi = 0; fi < 2; ++fi)
#pragma unroll
                    for (int fj = 0; fj < 2; ++fj)
                        acc[fi][fj] = __builtin_amdgcn_mfma_f32_32x32x16_bf16(a_h[fi], b_h[fj], acc[fi][fj], 0, 0, 0);
            }
        }
        __syncthreads();
    }

    // epilogue; 32x32 C/D layout: col = l32, row = (reg&3) + 8*(reg>>2) + 4*khalf
    if (OUT != 2) {
        float* cf = (OUT == 0) ? Cf + (long)bz * sC : nullptr;
        unsigned short* ch = (OUT == 1) ? Ch + (long)bz * sC : nullptr;
        unsigned short* cl = (OUT == 1) ? Cl + (long)bz * sC : nullptr;
#pragma unroll
        for (int fj = 0; fj < 2; ++fj) {
            const int col = col0 + wn + fj * 32 + l32;
            const float bval = bias ? (col < nsplit ? bias[col] : bias2[col - nsplit]) : 0.0f;
#pragma unroll
            for (int fi = 0; fi < 2; ++fi) {
#pragma unroll
                for (int reg = 0; reg < 16; ++reg) {
                    const int row = row0 + wm + fi * 32 + (reg & 3) + 8 * (reg >> 2) + 4 * khalf;
                    const float v = acc[fi][fj][reg] + bval;
                    if (OUT == 0) {
                        cf[(long)row * ldc + col] = v;
                    } else {
                        const unsigned short h = f2bf(v);
                        ch[(long)row * ldc + col] = h;
                        cl[(long)row * ldc + col] = f2bf(v - bf2f(h));
                    }
                }
            }
        }
    } else {
        // transpose through LDS (XOR-swizzled, low-3-bit-preserving)
#pragma unroll
        for (int fj = 0; fj < 2; ++fj) {
            const int cl_ = wn + fj * 32 + l32;
            const float bval = bias ? bias[col0 + cl_] : 0.0f;
#pragma unroll
            for (int fi = 0; fi < 2; ++fi) {
#pragma unroll
                for (int reg = 0; reg < 16; ++reg) {
                    const int sl = wm + fi * 32 + (reg & 3) + 8 * (reg >> 2) + 4 * khalf;
                    sVt[cl_ * TM + (sl ^ ((cl_ & 15) << 3))] = f2bf(acc[fi][fj][reg] + bval);
                }
            }
        }
        __syncthreads();
        const int bb = row0 / batchS;              // tiles never cross batches
        const int sbase = row0 - bb * batchS;
        for (int idx = tid; idx < TM * TN / 8; idx += 256) {
            const int cl_ = idx >> 4, s0 = (idx & 15) << 3;
            u16x8 v = *(const u16x8*)&sVt[cl_ * TM + (s0 ^ ((cl_ & 15) << 3))];
            *(u16x8*)&Ch[(long)bb * sC + (long)(col0 + cl_) * batchS + sbase + s0] = v;
        }
    }
}

// ---------------------------------------------------------------------------
// softmax: causal, reads fp32 Sc row, writes bf16 P row; writes exactly the
// columns the PV GEMM will read (k_end = ceil((r+1)/128)*128), zeros past r.
// ---------------------------------------------------------------------------
__global__ __launch_bounds__(256)
void softmax_kernel(const float* __restrict__ Sc, unsigned short* __restrict__ P, int seq)
{
    const int r = blockIdx.x, b = blockIdx.y;
    const float* row = Sc + ((long)b * seq + r) * seq;
    unsigned short* prow = P + ((long)b * seq + r) * seq;
    const int tid = threadIdx.x;
    const int cmax = ((r >> 7) + 1) << 7;

    float v[8];
    const f32x4* rp = (const f32x4*)row;
    f32x4 v0 = rp[tid * 2], v1 = rp[tid * 2 + 1];
    const int c0 = tid * 8;
    float lmax = -3.0e38f;
#pragma unroll
    for (int k = 0; k < 4; ++k) {
        v[k]     = (c0 + k     <= r) ? v0[k] : -3.0e38f;
        v[k + 4] = (c0 + k + 4 <= r) ? v1[k] : -3.0e38f;
    }
#pragma unroll
    for (int k = 0; k < 8; ++k) lmax = fmaxf(lmax, v[k]);

    __shared__ float red[256];
    red[tid] = lmax; __syncthreads();
    for (int s = 128; s > 0; s >>= 1) {
        if (tid < s) red[tid] = fmaxf(red[tid], red[tid + s]);
        __syncthreads();
    }
    const float m = red[0];
    __syncthreads();

    float lsum = 0.0f;
#pragma unroll
    for (int k = 0; k < 8; ++k) {
        float e = (v[k] > -1.0e38f) ? __expf(v[k] - m) : 0.0f;
        v[k] = e;
        lsum += e;
    }
    red[tid] = lsum; __syncthreads();
    for (int s = 128; s > 0; s >>= 1) {
        if (tid < s) red[tid] += red[tid + s];
        __syncthreads();
    }
    const float inv = 1.0f / red[0];

    if (c0 < cmax) {
        u16x4 o0, o1;
#pragma unroll
        for (int k = 0; k < 4; ++k) {
            o0[k] = f2bf(v[k] * inv);
            o1[k] = f2bf(v[k + 4] * inv);
        }
        ((u16x4*)prow)[tid * 2]     = o0;
        ((u16x4*)prow)[tid * 2 + 1] = o1;
    }
}

// ---------------------------------------------------------------------------
extern "C" void kernel_launch(void* const* d_in, const int* in_sizes, int n_in,
                              void* d_out, int out_size, void* d_ws, size_t ws_size,
                              hipStream_t stream)
{
    constexpr int B = 4, S = 2048, D = 1024;
    constexpr long MB = 1024 * 1024;
    const float* x  = (const float*)d_in[0];
    const float* Wq = (const float*)d_in[1];
    const float* bq = (const float*)d_in[2];
    const float* Wk = (const float*)d_in[3];
    const float* bk = (const float*)d_in[4];
    const float* Wv = (const float*)d_in[5];
    const float* bv = (const float*)d_in[6];
    float* out = (float*)d_out;

    // workspace layout (144 MB; Sc overlaps dead x/W; P overlaps dead QK_lo)
    char* ws = (char*)d_ws;
    unsigned short* x_hi   = (unsigned short*)(ws + 0);        // 16 MB
    unsigned short* x_lo   = (unsigned short*)(ws + 16 * MB);  // 16 MB
    unsigned short* Wqkt_h = (unsigned short*)(ws + 32 * MB);  // 4 MB  [2048][1024]
    unsigned short* Wqkt_l = (unsigned short*)(ws + 36 * MB);  // 4 MB
    unsigned short* Wvt_h  = (unsigned short*)(ws + 40 * MB);  // 2 MB
    float*          Sc     = (float*)(ws + 0);                 // 64 MB, after x/W dead
    unsigned short* QK_h   = (unsigned short*)(ws + 64 * MB);  // 32 MB [M][2048]
    unsigned short* QK_l   = (unsigned short*)(ws + 96 * MB);  // 32 MB
    unsigned short* Vt     = (unsigned short*)(ws + 128 * MB); // 16 MB [B][D][S]
    unsigned short* P      = QK_l;                             // 32 MB, after scores

    const int M = B * S;  // 8192
    const int NONE = 1 << 30;
    dim3 blk(256);

    // 1) convert x -> hi/lo bf16
    convert_split<<<(M * D / 4 + 255) / 256, blk, 0, stream>>>(x, x_hi, x_lo, (long)M * D / 4);
    // 2) transpose+convert weights -> [n][k] bf16 (Wq,Wk stacked into one [2048][1024])
    dim3 tgrid(D / 32, D / 32);
    transpose_w<true ><<<tgrid, blk, 0, stream>>>(Wq, Wqkt_h, Wqkt_l, D);
    transpose_w<true ><<<tgrid, blk, 0, stream>>>(Wk, Wqkt_h + (long)D * D, Wqkt_l + (long)D * D, D);
    transpose_w<false><<<tgrid, blk, 0, stream>>>(Wv, Wvt_h, nullptr, D);

    // 3) merged QK projection: [M][1024] @ [2048][1024]^T -> QK [M][2048] hi/lo
    gemm2<true, 0, 1><<<dim3(2 * D / TN, M / TM, 1), blk, 0, stream>>>(
        x_hi, x_lo, 0, D, Wqkt_h, Wqkt_l, 0, D,
        nullptr, QK_h, QK_l, 0, 2 * D, D, bq, bk, D, S);
    // 3b) V projection -> Vt [B][D][S] bf16 (transposed epilogue)
    gemm2<false, 0, 2><<<dim3(D / TN, M / TM, 1), blk, 0, stream>>>(
        x_hi, nullptr, 0, D, Wvt_h, nullptr, 0, D,
        nullptr, Vt, nullptr, (long)D * S, D, D, bv, nullptr, NONE, S);

    // 4) scores = Q @ K^T (split, causal tiles only) -> fp32 Sc
    gemm2<true, 1, 0><<<dim3(S / TN, S / TM, B), blk, 0, stream>>>(
        QK_h, QK_l, (long)S * 2 * D, 2 * D, QK_h + D, QK_l + D, (long)S * 2 * D, 2 * D,
        Sc, nullptr, nullptr, (long)S * S, S, D, nullptr, nullptr, NONE, S);

    // 5) causal softmax: fp32 Sc -> bf16 P (writes exactly the PV-read columns)
    softmax_kernel<<<dim3(S, B), blk, 0, stream>>>(Sc, P, S);

    // 6) out = P @ V (K-loop bounded at diagonal)
    gemm2<false, 2, 0><<<dim3(D / TN, S / TM, B), blk, 0, stream>>>(
        P, nullptr, (long)S * S, S, Vt, nullptr, (long)D * S, S,
        out, nullptr, nullptr, (long)S * D, D, S, nullptr, nullptr, NONE, S);
}

// Round 4
// 424.690 us; speedup vs baseline: 1.0705x; 1.0705x over previous
//
#include <hip/hip_runtime.h>
#include <hip/hip_bf16.h>

typedef float f32x4  __attribute__((ext_vector_type(4)));
typedef short bf16x8 __attribute__((ext_vector_type(8)));
typedef unsigned short u16x4 __attribute__((ext_vector_type(4)));
typedef unsigned short u16x8 __attribute__((ext_vector_type(8)));

__device__ inline unsigned short f2bf(float v) {
    __hip_bfloat16 h = __float2bfloat16(v);
    return *reinterpret_cast<unsigned short*>(&h);
}
__device__ inline float bf2f(unsigned short u) {
    __hip_bfloat16 h;
    *reinterpret_cast<unsigned short*>(&h) = u;
    return __bfloat162float(h);
}

// ---------------------------------------------------------------------------
// convert_split: fp32 -> bf16 hi + lo (elementwise), float4-vectorized
// ---------------------------------------------------------------------------
__global__ __launch_bounds__(256)
void convert_split(const float* __restrict__ X, unsigned short* __restrict__ H,
                   unsigned short* __restrict__ L, long n4)
{
    long i = (long)blockIdx.x * 256 + threadIdx.x;
    if (i >= n4) return;
    f32x4 v = ((const f32x4*)X)[i];
    u16x4 h, l;
#pragma unroll
    for (int k = 0; k < 4; ++k) {
        h[k] = f2bf(v[k]);
        l[k] = f2bf(v[k] - bf2f(h[k]));
    }
    ((u16x4*)H)[i] = h;
    ((u16x4*)L)[i] = l;
}

// ---------------------------------------------------------------------------
// transpose_w: W [D][D] fp32 row-major -> Wt [n][k] bf16 hi (+lo if SPL)
// ---------------------------------------------------------------------------
template<bool SPL>
__global__ __launch_bounds__(256)
void transpose_w(const float* __restrict__ W, unsigned short* __restrict__ Th,
                 unsigned short* __restrict__ Tl, int D)
{
    __shared__ float t[32][33];
    const int tid = threadIdx.x;
    const int bx = blockIdx.x * 32, by = blockIdx.y * 32;
    const int c = tid & 31, r0 = tid >> 5;
#pragma unroll
    for (int r = r0; r < 32; r += 8)
        t[r][c] = W[(long)(by + r) * D + bx + c];
    __syncthreads();
#pragma unroll
    for (int r = r0; r < 32; r += 8) {
        float v = t[c][r];                       // = W[by+c][bx+r]
        unsigned short h = f2bf(v);
        Th[(long)(bx + r) * D + by + c] = h;     // Wt[n=bx+r][k=by+c]
        if (SPL) Tl[(long)(bx + r) * D + by + c] = f2bf(v - bf2f(h));
    }
}

// ---------------------------------------------------------------------------
// gemm2: C = A @ B^T_layout (+bias). A bf16 [M][K] row-major (hi, + lo if SPLIT),
// B bf16 [N][K] row-major (hi, + lo). TM=128 x TNB tile, TK=32, 16x16x32 MFMA,
// global_load_lds width-16 staging.
// MODE: 0 plain grid (x=cols,y=rows); 1 causal packed triangular grid
//       (x = linear live-tile id, TNB=64, tiles/row = 2*rt+2);
//       2 PV: grid (x=rows heavy-first, y=cols), K-loop bounded at (rt+1)*TM.
// OUT:  0 fp32 Cf[ldc]; 1 split bf16 Ch/Cl[ldc]; 2 transposed bf16 Ch[b][col][s]
//       (via XOR-swizzled LDS, coalesced 16B stores).
// bias: col < nsplit -> bias[col], else bias2[col-nsplit]  (merged QK biases).
// ---------------------------------------------------------------------------
constexpr int TM = 128, TK = 32;

template<bool SPLIT, int MODE, int OUT, int TNB>
__global__ __launch_bounds__(256)
void gemm2(const unsigned short* __restrict__ Ah, const unsigned short* __restrict__ Al,
           long sA, int lda,
           const unsigned short* __restrict__ Bh, const unsigned short* __restrict__ Bl,
           long sB, int ldb,
           float* __restrict__ Cf, unsigned short* __restrict__ Ch, unsigned short* __restrict__ Cl,
           long sC, int ldc, int K,
           const float* __restrict__ bias, const float* __restrict__ bias2, int nsplit,
           int batchS)
{
    static_assert(MODE != 1 || TNB == 64, "packed causal decode assumes TNB=64");
    constexpr int NFJ = TNB / 32;     // B fragments per wave
    constexpr int BRNDS = TNB / 64;   // B staging rounds

    int rt, ct;
    if (MODE == 1) {
        const int t = blockIdx.x;
        rt = (int)((sqrtf(4.0f * t + 1.0f) - 1.0f) * 0.5f);
        while (rt * (rt + 1) > t) --rt;
        while ((rt + 1) * (rt + 2) <= t) ++rt;
        ct = t - rt * (rt + 1);
    } else if (MODE == 2) {
        rt = (gridDim.x - 1) - blockIdx.x;   // heavy rows first
        ct = blockIdx.y;
    } else {
        rt = blockIdx.y; ct = blockIdx.x;
    }
    const int bz = blockIdx.z;

    const unsigned short* gAh = Ah + (long)bz * sA;
    const unsigned short* gAl = SPLIT ? Al + (long)bz * sA : nullptr;
    const unsigned short* gBh = Bh + (long)bz * sB;
    const unsigned short* gBl = SPLIT ? Bl + (long)bz * sB : nullptr;

    const int row0 = rt * TM, col0 = ct * TNB;
    const int k_end = (MODE == 2) ? min(K, (rt + 1) * TM) : K;

    __shared__ unsigned short sAh[TM * TK];                  // 8 KB, 64 B rows, unpadded
    __shared__ unsigned short sBh[TNB * TK];
    __shared__ unsigned short sAl[SPLIT ? TM * TK : 8];
    __shared__ unsigned short sBl[SPLIT ? TNB * TK : 8];
    __shared__ unsigned short sVt[OUT == 2 ? TM * TNB : 8];  // transpose staging

    const int tid = threadIdx.x;
    const int lane = tid & 63, wave = tid >> 6;
    const int l16 = lane & 15, quad = lane >> 4;
    const int wm = (wave >> 1) * 64, wn = (wave & 1) * (TNB / 2);

    f32x4 acc[4][NFJ] = {};

    for (int k0 = 0; k0 < k_end; k0 += TK) {
        // stage A: 128x32 bf16 (2 rounds of 256 lanes x 16 B)
#pragma unroll
        for (int rnd = 0; rnd < 2; ++rnd) {
            const int row = rnd * 64 + (tid >> 2);
            const long gA = (long)(row0 + row) * lda + k0 + (tid & 3) * 8;
            const int lofs = rnd * 2048 + tid * 8;
            __builtin_amdgcn_global_load_lds(
                (const __attribute__((address_space(1))) void*)(gAh + gA),
                (__attribute__((address_space(3))) void*)(sAh + lofs), 16, 0, 0);
            if (SPLIT)
                __builtin_amdgcn_global_load_lds(
                    (const __attribute__((address_space(1))) void*)(gAl + gA),
                    (__attribute__((address_space(3))) void*)(sAl + lofs), 16, 0, 0);
        }
        // stage B: TNBx32 bf16
#pragma unroll
        for (int rnd = 0; rnd < BRNDS; ++rnd) {
            const int row = rnd * 64 + (tid >> 2);
            const long gB = (long)(col0 + row) * ldb + k0 + (tid & 3) * 8;
            const int lofs = rnd * 2048 + tid * 8;
            __builtin_amdgcn_global_load_lds(
                (const __attribute__((address_space(1))) void*)(gBh + gB),
                (__attribute__((address_space(3))) void*)(sBh + lofs), 16, 0, 0);
            if (SPLIT)
                __builtin_amdgcn_global_load_lds(
                    (const __attribute__((address_space(1))) void*)(gBl + gB),
                    (__attribute__((address_space(3))) void*)(sBl + lofs), 16, 0, 0);
        }
        __syncthreads();

        // fragments: A[m=l16][k=quad*8+j], B[n=l16][k=quad*8+j]
        bf16x8 a_h[4], b_h[NFJ];
#pragma unroll
        for (int i = 0; i < 4; ++i)
            a_h[i] = *(const bf16x8*)&sAh[(wm + i * 16 + l16) * TK + (quad << 3)];
#pragma unroll
        for (int j = 0; j < NFJ; ++j)
            b_h[j] = *(const bf16x8*)&sBh[(wn + j * 16 + l16) * TK + (quad << 3)];

        if (SPLIT) {
            bf16x8 a_l[4], b_l[NFJ];
#pragma unroll
            for (int i = 0; i < 4; ++i)
                a_l[i] = *(const bf16x8*)&sAl[(wm + i * 16 + l16) * TK + (quad << 3)];
#pragma unroll
            for (int j = 0; j < NFJ; ++j)
                b_l[j] = *(const bf16x8*)&sBl[(wn + j * 16 + l16) * TK + (quad << 3)];
#pragma unroll
            for (int i = 0; i < 4; ++i)
#pragma unroll
                for (int j = 0; j < NFJ; ++j) {
                    acc[i][j] = __builtin_amdgcn_mfma_f32_16x16x32_bf16(a_h[i], b_h[j], acc[i][j], 0, 0, 0);
                    acc[i][j] = __builtin_amdgcn_mfma_f32_16x16x32_bf16(a_h[i], b_l[j], acc[i][j], 0, 0, 0);
                    acc[i][j] = __builtin_amdgcn_mfma_f32_16x16x32_bf16(a_l[i], b_h[j], acc[i][j], 0, 0, 0);
                }
        } else {
#pragma unroll
            for (int i = 0; i < 4; ++i)
#pragma unroll
                for (int j = 0; j < NFJ; ++j)
                    acc[i][j] = __builtin_amdgcn_mfma_f32_16x16x32_bf16(a_h[i], b_h[j], acc[i][j], 0, 0, 0);
        }
        __syncthreads();
    }

    // epilogue; 16x16 C/D layout: col = l16, row = quad*4 + r
    if (OUT != 2) {
        float* cf = (OUT == 0) ? Cf + (long)bz * sC : nullptr;
        unsigned short* ch = (OUT == 1) ? Ch + (long)bz * sC : nullptr;
        unsigned short* cl = (OUT == 1) ? Cl + (long)bz * sC : nullptr;
#pragma unroll
        for (int j = 0; j < NFJ; ++j) {
            const int col = col0 + wn + j * 16 + l16;
            const float bval = bias ? (col < nsplit ? bias[col] : bias2[col - nsplit]) : 0.0f;
#pragma unroll
            for (int i = 0; i < 4; ++i) {
                const int rb = row0 + wm + i * 16 + quad * 4;
#pragma unroll
                for (int r = 0; r < 4; ++r) {
                    const float v = acc[i][j][r] + bval;
                    if (OUT == 0) {
                        cf[(long)(rb + r) * ldc + col] = v;
                    } else {
                        const unsigned short h = f2bf(v);
                        ch[(long)(rb + r) * ldc + col] = h;
                        cl[(long)(rb + r) * ldc + col] = f2bf(v - bf2f(h));
                    }
                }
            }
        }
    } else {
        // transpose through LDS (XOR swizzle preserves 8-elem alignment)
#pragma unroll
        for (int j = 0; j < NFJ; ++j) {
            const int cl_ = wn + j * 16 + l16;
            const float bval = bias ? bias[col0 + cl_] : 0.0f;
#pragma unroll
            for (int i = 0; i < 4; ++i) {
#pragma unroll
                for (int r = 0; r < 4; ++r) {
                    const int sl = wm + i * 16 + quad * 4 + r;
                    sVt[cl_ * TM + (sl ^ ((cl_ & 15) << 3))] = f2bf(acc[i][j][r] + bval);
                }
            }
        }
        __syncthreads();
        const int bb = row0 / batchS;              // tiles never cross batches
        const int sbase = row0 - bb * batchS;
        for (int idx = tid; idx < TNB * (TM / 8); idx += 256) {
            const int cl_ = idx >> 4, s0 = (idx & 15) << 3;
            u16x8 v = *(const u16x8*)&sVt[cl_ * TM + (s0 ^ ((cl_ & 15) << 3))];
            *(u16x8*)&Ch[(long)bb * sC + (long)(col0 + cl_) * batchS + sbase + s0] = v;
        }
    }
}

// ---------------------------------------------------------------------------
// softmax: causal, reads fp32 Sc row, writes bf16 P row; writes exactly the
// columns the PV GEMM will read (ceil((r+1)/128)*128), zeros past r.
// ---------------------------------------------------------------------------
__global__ __launch_bounds__(256)
void softmax_kernel(const float* __restrict__ Sc, unsigned short* __restrict__ P, int seq)
{
    const int r = blockIdx.x, b = blockIdx.y;
    const float* row = Sc + ((long)b * seq + r) * seq;
    unsigned short* prow = P + ((long)b * seq + r) * seq;
    const int tid = threadIdx.x;
    const int cmax = ((r >> 7) + 1) << 7;

    float v[8];
    const f32x4* rp = (const f32x4*)row;
    f32x4 v0 = rp[tid * 2], v1 = rp[tid * 2 + 1];
    const int c0 = tid * 8;
    float lmax = -3.0e38f;
#pragma unroll
    for (int k = 0; k < 4; ++k) {
        v[k]     = (c0 + k     <= r) ? v0[k] : -3.0e38f;
        v[k + 4] = (c0 + k + 4 <= r) ? v1[k] : -3.0e38f;
    }
#pragma unroll
    for (int k = 0; k < 8; ++k) lmax = fmaxf(lmax, v[k]);

    __shared__ float red[256];
    red[tid] = lmax; __syncthreads();
    for (int s = 128; s > 0; s >>= 1) {
        if (tid < s) red[tid] = fmaxf(red[tid], red[tid + s]);
        __syncthreads();
    }
    const float m = red[0];
    __syncthreads();

    float lsum = 0.0f;
#pragma unroll
    for (int k = 0; k < 8; ++k) {
        float e = (v[k] > -1.0e38f) ? __expf(v[k] - m) : 0.0f;
        v[k] = e;
        lsum += e;
    }
    red[tid] = lsum; __syncthreads();
    for (int s = 128; s > 0; s >>= 1) {
        if (tid < s) red[tid] += red[tid + s];
        __syncthreads();
    }
    const float inv = 1.0f / red[0];

    if (c0 < cmax) {
        u16x4 o0, o1;
#pragma unroll
        for (int k = 0; k < 4; ++k) {
            o0[k] = f2bf(v[k] * inv);
            o1[k] = f2bf(v[k + 4] * inv);
        }
        ((u16x4*)prow)[tid * 2]     = o0;
        ((u16x4*)prow)[tid * 2 + 1] = o1;
    }
}

// ---------------------------------------------------------------------------
extern "C" void kernel_launch(void* const* d_in, const int* in_sizes, int n_in,
                              void* d_out, int out_size, void* d_ws, size_t ws_size,
                              hipStream_t stream)
{
    constexpr int B = 4, S = 2048, D = 1024;
    constexpr long MB = 1024 * 1024;
    const float* x  = (const float*)d_in[0];
    const float* Wq = (const float*)d_in[1];
    const float* bq = (const float*)d_in[2];
    const float* Wk = (const float*)d_in[3];
    const float* bk = (const float*)d_in[4];
    const float* Wv = (const float*)d_in[5];
    const float* bv = (const float*)d_in[6];
    float* out = (float*)d_out;

    // workspace layout (144 MB; Sc overlaps dead x/W; P overlaps dead QK_lo)
    char* ws = (char*)d_ws;
    unsigned short* x_hi   = (unsigned short*)(ws + 0);        // 16 MB
    unsigned short* x_lo   = (unsigned short*)(ws + 16 * MB);  // 16 MB
    unsigned short* Wqkt_h = (unsigned short*)(ws + 32 * MB);  // 4 MB  [2048][1024]
    unsigned short* Wqkt_l = (unsigned short*)(ws + 36 * MB);  // 4 MB
    unsigned short* Wvt_h  = (unsigned short*)(ws + 40 * MB);  // 2 MB
    float*          Sc     = (float*)(ws + 0);                 // 64 MB, after x/W dead
    unsigned short* QK_h   = (unsigned short*)(ws + 64 * MB);  // 32 MB [M][2048]
    unsigned short* QK_l   = (unsigned short*)(ws + 96 * MB);  // 32 MB
    unsigned short* Vt     = (unsigned short*)(ws + 128 * MB); // 16 MB [B][D][S]
    unsigned short* P      = QK_l;                             // 32 MB, after scores

    const int M = B * S;  // 8192
    const int NONE = 1 << 30;
    dim3 blk(256);

    // 1) convert x -> hi/lo bf16
    convert_split<<<(M * D / 4 + 255) / 256, blk, 0, stream>>>(x, x_hi, x_lo, (long)M * D / 4);
    // 2) transpose+convert weights -> [n][k] bf16 (Wq,Wk stacked into [2048][1024])
    dim3 tgrid(D / 32, D / 32);
    transpose_w<true ><<<tgrid, blk, 0, stream>>>(Wq, Wqkt_h, Wqkt_l, D);
    transpose_w<true ><<<tgrid, blk, 0, stream>>>(Wk, Wqkt_h + (long)D * D, Wqkt_l + (long)D * D, D);
    transpose_w<false><<<tgrid, blk, 0, stream>>>(Wv, Wvt_h, nullptr, D);

    // 3) merged QK projection: [M][1024] @ [2048][1024]^T -> QK [M][2048] hi/lo
    gemm2<true, 0, 1, 128><<<dim3(2 * D / 128, M / TM, 1), blk, 0, stream>>>(
        x_hi, x_lo, 0, D, Wqkt_h, Wqkt_l, 0, D,
        nullptr, QK_h, QK_l, 0, 2 * D, D, bq, bk, D, S);
    // 3b) V projection -> Vt [B][D][S] bf16 (transposed epilogue, TN=64)
    gemm2<false, 0, 2, 64><<<dim3(D / 64, M / TM, 1), blk, 0, stream>>>(
        x_hi, nullptr, 0, D, Wvt_h, nullptr, 0, D,
        nullptr, Vt, nullptr, (long)D * S, D, D, bv, nullptr, NONE, S);

    // 4) scores = Q @ K^T (split, packed triangular grid, TN=64) -> fp32 Sc
    const int ntiles = (S / TM) * (S / TM + 1);   // 16*17 = 272 live 128x64 tiles
    gemm2<true, 1, 0, 64><<<dim3(ntiles, 1, B), blk, 0, stream>>>(
        QK_h, QK_l, (long)S * 2 * D, 2 * D, QK_h + D, QK_l + D, (long)S * 2 * D, 2 * D,
        Sc, nullptr, nullptr, (long)S * S, S, D, nullptr, nullptr, NONE, S);

    // 5) causal softmax: fp32 Sc -> bf16 P (writes exactly the PV-read columns)
    softmax_kernel<<<dim3(S, B), blk, 0, stream>>>(Sc, P, S);

    // 6) out = P @ V (K-loop bounded at diagonal, heavy rows first, TN=64)
    gemm2<false, 2, 0, 64><<<dim3(S / TM, D / 64, B), blk, 0, stream>>>(
        P, nullptr, (long)S * S, S, Vt, nullptr, (long)D * S, S,
        out, nullptr, nullptr, (long)S * D, D, S, nullptr, nullptr, NONE, S);
}

// Round 5
// 403.953 us; speedup vs baseline: 1.1254x; 1.0513x over previous
//
#include <hip/hip_runtime.h>
#include <hip/hip_bf16.h>

typedef float f32x4  __attribute__((ext_vector_type(4)));
typedef short bf16x8 __attribute__((ext_vector_type(8)));
typedef unsigned short u16x4 __attribute__((ext_vector_type(4)));
typedef unsigned short u16x8 __attribute__((ext_vector_type(8)));

__device__ inline unsigned short f2bf(float v) {
    __hip_bfloat16 h = __float2bfloat16(v);
    return *reinterpret_cast<unsigned short*>(&h);
}
__device__ inline float bf2f(unsigned short u) {
    __hip_bfloat16 h;
    *reinterpret_cast<unsigned short*>(&h) = u;
    return __bfloat162float(h);
}
__device__ inline void load_lds16(const unsigned short* g, unsigned short* l) {
    __builtin_amdgcn_global_load_lds((const __attribute__((address_space(1))) void*)g,
                                     (__attribute__((address_space(3))) void*)l, 16, 0, 0);
}

// ---------------------------------------------------------------------------
// convert_split: fp32 -> bf16 hi + lo (elementwise), float4-vectorized
// ---------------------------------------------------------------------------
__global__ __launch_bounds__(256)
void convert_split(const float* __restrict__ X, unsigned short* __restrict__ H,
                   unsigned short* __restrict__ L, long n4)
{
    long i = (long)blockIdx.x * 256 + threadIdx.x;
    if (i >= n4) return;
    f32x4 v = ((const f32x4*)X)[i];
    u16x4 h, l;
#pragma unroll
    for (int k = 0; k < 4; ++k) {
        h[k] = f2bf(v[k]);
        l[k] = f2bf(v[k] - bf2f(h[k]));
    }
    ((u16x4*)H)[i] = h;
    ((u16x4*)L)[i] = l;
}

// ---------------------------------------------------------------------------
// transpose_w3: all three W [D][D] fp32 -> Wt [n][k] bf16 hi+lo in ONE dispatch
// (z=0: Wq -> Hqk; z=1: Wk -> Hqk+D*D; z=2: Wv -> Hv)
// ---------------------------------------------------------------------------
__global__ __launch_bounds__(256)
void transpose_w3(const float* __restrict__ Wq, const float* __restrict__ Wk,
                  const float* __restrict__ Wv,
                  unsigned short* __restrict__ Hqk, unsigned short* __restrict__ Lqk,
                  unsigned short* __restrict__ Hv,  unsigned short* __restrict__ Lv,
                  int D)
{
    const int z = blockIdx.z;
    const float* W = (z == 0) ? Wq : (z == 1) ? Wk : Wv;
    unsigned short* Th = (z == 0) ? Hqk : (z == 1) ? Hqk + (long)D * D : Hv;
    unsigned short* Tl = (z == 0) ? Lqk : (z == 1) ? Lqk + (long)D * D : Lv;

    __shared__ float t[32][33];
    const int tid = threadIdx.x;
    const int bx = blockIdx.x * 32, by = blockIdx.y * 32;
    const int c = tid & 31, r0 = tid >> 5;
#pragma unroll
    for (int r = r0; r < 32; r += 8)
        t[r][c] = W[(long)(by + r) * D + bx + c];
    __syncthreads();
#pragma unroll
    for (int r = r0; r < 32; r += 8) {
        float v = t[c][r];                       // = W[by+c][bx+r]
        unsigned short h = f2bf(v);
        Th[(long)(bx + r) * D + by + c] = h;     // Wt[n=bx+r][k=by+c]
        Tl[(long)(bx + r) * D + by + c] = f2bf(v - bf2f(h));
    }
}

// ---------------------------------------------------------------------------
// proj_fused: one dispatch for all projections. grid = (24, 64).
//   ct 0..15 : split-bf16 QK projection -> QK_h/QK_l [M][2048] (3-MFMA split)
//   ct 16..23: single-bf16 V projection -> Vt [B][D][S] (transposed epilogue)
// 128x128 tile, TK=32, 16x16x32 MFMA, global_load_lds width-16 staging.
// ---------------------------------------------------------------------------
constexpr int TM = 128, TK = 32;

__global__ __launch_bounds__(256)
void proj_fused(const unsigned short* __restrict__ x_hi, const unsigned short* __restrict__ x_lo,
                const unsigned short* __restrict__ Wqk_h, const unsigned short* __restrict__ Wqk_l,
                const unsigned short* __restrict__ Wv_h,
                unsigned short* __restrict__ QK_h, unsigned short* __restrict__ QK_l,
                unsigned short* __restrict__ Vt,
                const float* __restrict__ bq, const float* __restrict__ bk,
                const float* __restrict__ bv)
{
    constexpr int D = 1024, SEQ = 2048;
    const int ct = blockIdx.x, rt = blockIdx.y;
    const bool split = ct < 16;
    const int row0 = rt * TM;
    const int col0 = (split ? ct : ct - 16) * TM;

    __shared__ __align__(16) unsigned short smem[16384];   // 32 KB, aliased
    unsigned short* sAh = smem;
    unsigned short* sBh = smem + 4096;
    unsigned short* sAl = smem + 8192;
    unsigned short* sBl = smem + 12288;

    const int tid = threadIdx.x;
    const int lane = tid & 63, wave = tid >> 6;
    const int l16 = lane & 15, quad = lane >> 4;
    const int wm = (wave >> 1) * 64, wn = (wave & 1) * 64;

    f32x4 acc[4][4] = {};

    if (split) {
        for (int k0 = 0; k0 < D; k0 += TK) {
#pragma unroll
            for (int rnd = 0; rnd < 2; ++rnd) {
                const int row = rnd * 64 + (tid >> 2);
                const long gA = (long)(row0 + row) * D + k0 + (tid & 3) * 8;
                const long gB = (long)(col0 + row) * D + k0 + (tid & 3) * 8;
                const int lofs = rnd * 2048 + tid * 8;
                load_lds16(x_hi + gA, sAh + lofs);
                load_lds16(x_lo + gA, sAl + lofs);
                load_lds16(Wqk_h + gB, sBh + lofs);
                load_lds16(Wqk_l + gB, sBl + lofs);
            }
            __syncthreads();
            bf16x8 a_h[4], b_h[4], a_l[4], b_l[4];
#pragma unroll
            for (int i = 0; i < 4; ++i) {
                a_h[i] = *(const bf16x8*)&sAh[(wm + i * 16 + l16) * TK + (quad << 3)];
                a_l[i] = *(const bf16x8*)&sAl[(wm + i * 16 + l16) * TK + (quad << 3)];
            }
#pragma unroll
            for (int j = 0; j < 4; ++j) {
                b_h[j] = *(const bf16x8*)&sBh[(wn + j * 16 + l16) * TK + (quad << 3)];
                b_l[j] = *(const bf16x8*)&sBl[(wn + j * 16 + l16) * TK + (quad << 3)];
            }
#pragma unroll
            for (int i = 0; i < 4; ++i)
#pragma unroll
                for (int j = 0; j < 4; ++j) {
                    acc[i][j] = __builtin_amdgcn_mfma_f32_16x16x32_bf16(a_h[i], b_h[j], acc[i][j], 0, 0, 0);
                    acc[i][j] = __builtin_amdgcn_mfma_f32_16x16x32_bf16(a_h[i], b_l[j], acc[i][j], 0, 0, 0);
                    acc[i][j] = __builtin_amdgcn_mfma_f32_16x16x32_bf16(a_l[i], b_h[j], acc[i][j], 0, 0, 0);
                }
            __syncthreads();
        }
        // epilogue: split bf16 hi/lo scatter (L2 merges the 32B runs into full lines)
#pragma unroll
        for (int j = 0; j < 4; ++j) {
            const int col = col0 + wn + j * 16 + l16;
            const float bval = (col < D) ? bq[col] : bk[col - D];
#pragma unroll
            for (int i = 0; i < 4; ++i) {
                const int rb = row0 + wm + i * 16 + quad * 4;
#pragma unroll
                for (int r = 0; r < 4; ++r) {
                    const float v = acc[i][j][r] + bval;
                    const unsigned short h = f2bf(v);
                    QK_h[(long)(rb + r) * (2 * D) + col] = h;
                    QK_l[(long)(rb + r) * (2 * D) + col] = f2bf(v - bf2f(h));
                }
            }
        }
    } else {
        for (int k0 = 0; k0 < D; k0 += TK) {
#pragma unroll
            for (int rnd = 0; rnd < 2; ++rnd) {
                const int row = rnd * 64 + (tid >> 2);
                const long gA = (long)(row0 + row) * D + k0 + (tid & 3) * 8;
                const long gB = (long)(col0 + row) * D + k0 + (tid & 3) * 8;
                const int lofs = rnd * 2048 + tid * 8;
                load_lds16(x_hi + gA, sAh + lofs);
                load_lds16(Wv_h + gB, sBh + lofs);
            }
            __syncthreads();
            bf16x8 a_h[4], b_h[4];
#pragma unroll
            for (int i = 0; i < 4; ++i)
                a_h[i] = *(const bf16x8*)&sAh[(wm + i * 16 + l16) * TK + (quad << 3)];
#pragma unroll
            for (int j = 0; j < 4; ++j)
                b_h[j] = *(const bf16x8*)&sBh[(wn + j * 16 + l16) * TK + (quad << 3)];
#pragma unroll
            for (int i = 0; i < 4; ++i)
#pragma unroll
                for (int j = 0; j < 4; ++j)
                    acc[i][j] = __builtin_amdgcn_mfma_f32_16x16x32_bf16(a_h[i], b_h[j], acc[i][j], 0, 0, 0);
            __syncthreads();
        }
        // epilogue: transpose via XOR-swizzled LDS (aliases staging), 16B stores
        unsigned short* sVt = smem;   // 16384 shorts = full 128x128 bf16 tile
#pragma unroll
        for (int j = 0; j < 4; ++j) {
            const int cl_ = wn + j * 16 + l16;
            const float bval = bv[col0 + cl_];
#pragma unroll
            for (int i = 0; i < 4; ++i) {
#pragma unroll
                for (int r = 0; r < 4; ++r) {
                    const int sl = wm + i * 16 + quad * 4 + r;
                    sVt[cl_ * TM + (sl ^ ((cl_ & 15) << 3))] = f2bf(acc[i][j][r] + bval);
                }
            }
        }
        __syncthreads();
        const int bb = row0 / SEQ;                 // tiles never cross batches
        const int sbase = row0 - bb * SEQ;
        for (int idx = tid; idx < TM * TM / 8; idx += 256) {
            const int cl_ = idx >> 4, s0 = (idx & 15) << 3;
            u16x8 v = *(const u16x8*)&sVt[cl_ * TM + (s0 ^ ((cl_ & 15) << 3))];
            *(u16x8*)&Vt[(long)bb * D * SEQ + (long)(col0 + cl_) * SEQ + sbase + s0] = v;
        }
    }
}

// ---------------------------------------------------------------------------
// gemm2: C = A @ B^T_layout (fp32 out). A bf16 [M][K] (hi, + lo if SPLIT),
// B bf16 [N][K]. TM=128 x TNB, TK=32, 16x16x32 MFMA, global_load_lds staging.
// MODE 1: causal packed triangular grid (x = live-tile id, TNB=64);
// MODE 2: PV, grid (x=rows heavy-first, y=cols), K bounded at (rt+1)*TM.
// ---------------------------------------------------------------------------
template<bool SPLIT, int MODE, int TNB>
__global__ __launch_bounds__(256)
void gemm2(const unsigned short* __restrict__ Ah, const unsigned short* __restrict__ Al,
           long sA, int lda,
           const unsigned short* __restrict__ Bh, const unsigned short* __restrict__ Bl,
           long sB, int ldb,
           float* __restrict__ Cf, long sC, int ldc, int K)
{
    static_assert(MODE != 1 || TNB == 64, "packed causal decode assumes TNB=64");
    constexpr int NFJ = TNB / 32;
    constexpr int BRNDS = TNB / 64;

    int rt, ct;
    if (MODE == 1) {
        const int t = blockIdx.x;
        rt = (int)((sqrtf(4.0f * t + 1.0f) - 1.0f) * 0.5f);
        while (rt * (rt + 1) > t) --rt;
        while ((rt + 1) * (rt + 2) <= t) ++rt;
        ct = t - rt * (rt + 1);
    } else {
        rt = (gridDim.x - 1) - blockIdx.x;   // heavy rows first
        ct = blockIdx.y;
    }
    const int bz = blockIdx.z;

    const unsigned short* gAh = Ah + (long)bz * sA;
    const unsigned short* gAl = SPLIT ? Al + (long)bz * sA : nullptr;
    const unsigned short* gBh = Bh + (long)bz * sB;
    const unsigned short* gBl = SPLIT ? Bl + (long)bz * sB : nullptr;

    const int row0 = rt * TM, col0 = ct * TNB;
    const int k_end = (MODE == 2) ? min(K, (rt + 1) * TM) : K;

    __shared__ unsigned short sAh[TM * TK];
    __shared__ unsigned short sBh[TNB * TK];
    __shared__ unsigned short sAl[SPLIT ? TM * TK : 8];
    __shared__ unsigned short sBl[SPLIT ? TNB * TK : 8];

    const int tid = threadIdx.x;
    const int lane = tid & 63, wave = tid >> 6;
    const int l16 = lane & 15, quad = lane >> 4;
    const int wm = (wave >> 1) * 64, wn = (wave & 1) * (TNB / 2);

    f32x4 acc[4][NFJ] = {};

    for (int k0 = 0; k0 < k_end; k0 += TK) {
#pragma unroll
        for (int rnd = 0; rnd < 2; ++rnd) {
            const int row = rnd * 64 + (tid >> 2);
            const long gA = (long)(row0 + row) * lda + k0 + (tid & 3) * 8;
            const int lofs = rnd * 2048 + tid * 8;
            load_lds16(gAh + gA, sAh + lofs);
            if (SPLIT) load_lds16(gAl + gA, sAl + lofs);
        }
#pragma unroll
        for (int rnd = 0; rnd < BRNDS; ++rnd) {
            const int row = rnd * 64 + (tid >> 2);
            const long gB = (long)(col0 + row) * ldb + k0 + (tid & 3) * 8;
            const int lofs = rnd * 2048 + tid * 8;
            load_lds16(gBh + gB, sBh + lofs);
            if (SPLIT) load_lds16(gBl + gB, sBl + lofs);
        }
        __syncthreads();

        bf16x8 a_h[4], b_h[NFJ];
#pragma unroll
        for (int i = 0; i < 4; ++i)
            a_h[i] = *(const bf16x8*)&sAh[(wm + i * 16 + l16) * TK + (quad << 3)];
#pragma unroll
        for (int j = 0; j < NFJ; ++j)
            b_h[j] = *(const bf16x8*)&sBh[(wn + j * 16 + l16) * TK + (quad << 3)];

        if (SPLIT) {
            bf16x8 a_l[4], b_l[NFJ];
#pragma unroll
            for (int i = 0; i < 4; ++i)
                a_l[i] = *(const bf16x8*)&sAl[(wm + i * 16 + l16) * TK + (quad << 3)];
#pragma unroll
            for (int j = 0; j < NFJ; ++j)
                b_l[j] = *(const bf16x8*)&sBl[(wn + j * 16 + l16) * TK + (quad << 3)];
#pragma unroll
            for (int i = 0; i < 4; ++i)
#pragma unroll
                for (int j = 0; j < NFJ; ++j) {
                    acc[i][j] = __builtin_amdgcn_mfma_f32_16x16x32_bf16(a_h[i], b_h[j], acc[i][j], 0, 0, 0);
                    acc[i][j] = __builtin_amdgcn_mfma_f32_16x16x32_bf16(a_h[i], b_l[j], acc[i][j], 0, 0, 0);
                    acc[i][j] = __builtin_amdgcn_mfma_f32_16x16x32_bf16(a_l[i], b_h[j], acc[i][j], 0, 0, 0);
                }
        } else {
#pragma unroll
            for (int i = 0; i < 4; ++i)
#pragma unroll
                for (int j = 0; j < NFJ; ++j)
                    acc[i][j] = __builtin_amdgcn_mfma_f32_16x16x32_bf16(a_h[i], b_h[j], acc[i][j], 0, 0, 0);
        }
        __syncthreads();
    }

    float* cf = Cf + (long)bz * sC;
#pragma unroll
    for (int j = 0; j < NFJ; ++j) {
        const int col = col0 + wn + j * 16 + l16;
#pragma unroll
        for (int i = 0; i < 4; ++i) {
            const int rb = row0 + wm + i * 16 + quad * 4;
#pragma unroll
            for (int r = 0; r < 4; ++r)
                cf[(long)(rb + r) * ldc + col] = acc[i][j][r];
        }
    }
}

// ---------------------------------------------------------------------------
// softmax: causal, fp32 Sc row -> bf16 P row; loads only live 32B chunks,
// writes exactly the columns the PV GEMM will read (ceil((r+1)/128)*128).
// ---------------------------------------------------------------------------
__global__ __launch_bounds__(256)
void softmax_kernel(const float* __restrict__ Sc, unsigned short* __restrict__ P, int seq)
{
    const int r = blockIdx.x, b = blockIdx.y;
    const float* row = Sc + ((long)b * seq + r) * seq;
    unsigned short* prow = P + ((long)b * seq + r) * seq;
    const int tid = threadIdx.x;
    const int cmax = ((r >> 7) + 1) << 7;
    const int c0 = tid * 8;

    float v[8];
    f32x4 v0, v1;
    if (c0 <= r) {                 // chunk has at least one live column
        const f32x4* rp = (const f32x4*)row;
        v0 = rp[tid * 2];
        v1 = rp[tid * 2 + 1];
    } else {
        v0 = (f32x4)(-3.0e38f);
        v1 = (f32x4)(-3.0e38f);
    }
    float lmax = -3.0e38f;
#pragma unroll
    for (int k = 0; k < 4; ++k) {
        v[k]     = (c0 + k     <= r) ? v0[k] : -3.0e38f;
        v[k + 4] = (c0 + k + 4 <= r) ? v1[k] : -3.0e38f;
    }
#pragma unroll
    for (int k = 0; k < 8; ++k) lmax = fmaxf(lmax, v[k]);

    __shared__ float red[256];
    red[tid] = lmax; __syncthreads();
    for (int s = 128; s > 0; s >>= 1) {
        if (tid < s) red[tid] = fmaxf(red[tid], red[tid + s]);
        __syncthreads();
    }
    const float m = red[0];
    __syncthreads();

    float lsum = 0.0f;
#pragma unroll
    for (int k = 0; k < 8; ++k) {
        float e = (v[k] > -1.0e38f) ? __expf(v[k] - m) : 0.0f;
        v[k] = e;
        lsum += e;
    }
    red[tid] = lsum; __syncthreads();
    for (int s = 128; s > 0; s >>= 1) {
        if (tid < s) red[tid] += red[tid + s];
        __syncthreads();
    }
    const float inv = 1.0f / red[0];

    if (c0 < cmax) {
        u16x4 o0, o1;
#pragma unroll
        for (int k = 0; k < 4; ++k) {
            o0[k] = f2bf(v[k] * inv);
            o1[k] = f2bf(v[k + 4] * inv);
        }
        ((u16x4*)prow)[tid * 2]     = o0;
        ((u16x4*)prow)[tid * 2 + 1] = o1;
    }
}

// ---------------------------------------------------------------------------
extern "C" void kernel_launch(void* const* d_in, const int* in_sizes, int n_in,
                              void* d_out, int out_size, void* d_ws, size_t ws_size,
                              hipStream_t stream)
{
    constexpr int B = 4, S = 2048, D = 1024;
    constexpr long MB = 1024 * 1024;
    const float* x  = (const float*)d_in[0];
    const float* Wq = (const float*)d_in[1];
    const float* bq = (const float*)d_in[2];
    const float* Wk = (const float*)d_in[3];
    const float* bk = (const float*)d_in[4];
    const float* Wv = (const float*)d_in[5];
    const float* bv = (const float*)d_in[6];
    float* out = (float*)d_out;

    // workspace layout (144 MB; Sc overlaps dead x/W; P overlaps dead QK_lo)
    char* ws = (char*)d_ws;
    unsigned short* x_hi   = (unsigned short*)(ws + 0);        // 16 MB
    unsigned short* x_lo   = (unsigned short*)(ws + 16 * MB);  // 16 MB
    unsigned short* Wqkt_h = (unsigned short*)(ws + 32 * MB);  // 4 MB [2048][1024]
    unsigned short* Wqkt_l = (unsigned short*)(ws + 36 * MB);  // 4 MB
    unsigned short* Wvt_h  = (unsigned short*)(ws + 40 * MB);  // 2 MB
    unsigned short* Wvt_l  = (unsigned short*)(ws + 42 * MB);  // 2 MB (written, never read)
    float*          Sc     = (float*)(ws + 0);                 // 64 MB, after x/W dead
    unsigned short* QK_h   = (unsigned short*)(ws + 64 * MB);  // 32 MB [M][2048]
    unsigned short* QK_l   = (unsigned short*)(ws + 96 * MB);  // 32 MB
    unsigned short* Vt     = (unsigned short*)(ws + 128 * MB); // 16 MB [B][D][S]
    unsigned short* P      = QK_l;                             // 32 MB, after scores

    const int M = B * S;  // 8192
    dim3 blk(256);

    // 1) convert x -> hi/lo bf16
    convert_split<<<(M * D / 4 + 255) / 256, blk, 0, stream>>>(x, x_hi, x_lo, (long)M * D / 4);
    // 2) all weight transposes in one dispatch
    transpose_w3<<<dim3(D / 32, D / 32, 3), blk, 0, stream>>>(
        Wq, Wk, Wv, Wqkt_h, Wqkt_l, Wvt_h, Wvt_l, D);

    // 3) fused projections: QK (split, cols 0..15) + V (single, cols 16..23)
    proj_fused<<<dim3(24, M / TM), blk, 0, stream>>>(
        x_hi, x_lo, Wqkt_h, Wqkt_l, Wvt_h, QK_h, QK_l, Vt, bq, bk, bv);

    // 4) scores = Q @ K^T (split, packed triangular grid, TN=64) -> fp32 Sc
    const int ntiles = (S / TM) * (S / TM + 1);   // 272 live 128x64 tiles
    gemm2<true, 1, 64><<<dim3(ntiles, 1, B), blk, 0, stream>>>(
        QK_h, QK_l, (long)S * 2 * D, 2 * D, QK_h + D, QK_l + D, (long)S * 2 * D, 2 * D,
        Sc, (long)S * S, S, D);

    // 5) causal softmax: fp32 Sc -> bf16 P
    softmax_kernel<<<dim3(S, B), blk, 0, stream>>>(Sc, P, S);

    // 6) out = P @ V (K-loop bounded at diagonal, heavy rows first, TN=64)
    gemm2<false, 2, 64><<<dim3(S / TM, D / 64, B), blk, 0, stream>>>(
        P, nullptr, (long)S * S, S, Vt, nullptr, (long)D * S, S,
        out, (long)S * D, D, S);
}

// Round 6
// 345.907 us; speedup vs baseline: 1.3143x; 1.1678x over previous
//
#include <hip/hip_runtime.h>

typedef float f32x4  __attribute__((ext_vector_type(4)));
typedef _Float16 f16x8  __attribute__((ext_vector_type(8)));
typedef _Float16 f16x4v __attribute__((ext_vector_type(4)));
typedef _Float16 f16x8v __attribute__((ext_vector_type(8)));

__device__ inline void load_lds16(const _Float16* g, _Float16* l) {
    __builtin_amdgcn_global_load_lds((const __attribute__((address_space(1))) void*)g,
                                     (__attribute__((address_space(3))) void*)l, 16, 0, 0);
}

// ---------------------------------------------------------------------------
// convert_h: fp32 -> fp16 (hi only; A-side operands need no lo term)
// ---------------------------------------------------------------------------
__global__ __launch_bounds__(256)
void convert_h(const float* __restrict__ X, _Float16* __restrict__ H, long n4)
{
    long i = (long)blockIdx.x * 256 + threadIdx.x;
    if (i >= n4) return;
    f32x4 v = ((const f32x4*)X)[i];
    f16x4v h;
#pragma unroll
    for (int k = 0; k < 4; ++k) h[k] = (_Float16)v[k];
    ((f16x4v*)H)[i] = h;
}

// ---------------------------------------------------------------------------
// transpose_w3: W [D][D] fp32 -> Wt [n][k] fp16 hi (+lo for z<2) in ONE dispatch
// (z=0: Wq -> Hqk; z=1: Wk -> Hqk+D*D; z=2: Wv -> Hv, hi only)
// ---------------------------------------------------------------------------
__global__ __launch_bounds__(256)
void transpose_w3(const float* __restrict__ Wq, const float* __restrict__ Wk,
                  const float* __restrict__ Wv,
                  _Float16* __restrict__ Hqk, _Float16* __restrict__ Lqk,
                  _Float16* __restrict__ Hv, int D)
{
    const int z = blockIdx.z;
    const float* W = (z == 0) ? Wq : (z == 1) ? Wk : Wv;
    _Float16* Th = (z == 0) ? Hqk : (z == 1) ? Hqk + (long)D * D : Hv;
    _Float16* Tl = (z == 0) ? Lqk : (z == 1) ? Lqk + (long)D * D : nullptr;

    __shared__ float t[32][33];
    const int tid = threadIdx.x;
    const int bx = blockIdx.x * 32, by = blockIdx.y * 32;
    const int c = tid & 31, r0 = tid >> 5;
#pragma unroll
    for (int r = r0; r < 32; r += 8)
        t[r][c] = W[(long)(by + r) * D + bx + c];
    __syncthreads();
#pragma unroll
    for (int r = r0; r < 32; r += 8) {
        float v = t[c][r];                       // = W[by+c][bx+r]
        _Float16 h = (_Float16)v;
        Th[(long)(bx + r) * D + by + c] = h;     // Wt[n=bx+r][k=by+c]
        if (z < 2) Tl[(long)(bx + r) * D + by + c] = (_Float16)(v - (float)h);
    }
}

// ---------------------------------------------------------------------------
// proj_fused: one dispatch for all projections. grid = (24, 64).
//   ct 0..7  : Q proj, 2-term (x_h @ (W_h+W_l)) -> Q_h fp16 [M][1024]
//   ct 8..15 : K proj, 2-term -> K_h + K_l fp16 [M][1024] (split storage)
//   ct 16..23: V proj, 1-term -> Vt fp16 [B][D][S] (transposed epilogue)
// 128x128 tile, TK=32, 16x16x32 f16 MFMA, global_load_lds width-16 staging.
// ---------------------------------------------------------------------------
constexpr int TM = 128, TK = 32;

__global__ __launch_bounds__(256)
void proj_fused(const _Float16* __restrict__ x_h,
                const _Float16* __restrict__ Wqk_h, const _Float16* __restrict__ Wqk_l,
                const _Float16* __restrict__ Wv_h,
                _Float16* __restrict__ Q_h, _Float16* __restrict__ K_h,
                _Float16* __restrict__ K_l, _Float16* __restrict__ Vt,
                const float* __restrict__ bq, const float* __restrict__ bk,
                const float* __restrict__ bv)
{
    constexpr int D = 1024, SEQ = 2048;
    const int ct = blockIdx.x, rt = blockIdx.y;
    const bool qk = ct < 16;
    const int row0 = rt * TM;
    const int col0 = (qk ? ct : ct - 16) * TM;   // column in stacked-W space

    __shared__ __align__(16) _Float16 smem[16384];   // 32 KB, aliased
    _Float16* sA  = smem;            // x hi       (8 KB)
    _Float16* sBh = smem + 4096;     // W hi       (8 KB)
    _Float16* sBl = smem + 8192;     // W lo       (8 KB)

    const int tid = threadIdx.x;
    const int lane = tid & 63, wave = tid >> 6;
    const int l16 = lane & 15, quad = lane >> 4;
    const int wm = (wave >> 1) * 64, wn = (wave & 1) * 64;

    f32x4 acc[4][4] = {};

    if (qk) {
        for (int k0 = 0; k0 < D; k0 += TK) {
#pragma unroll
            for (int rnd = 0; rnd < 2; ++rnd) {
                const int row = rnd * 64 + (tid >> 2);
                const long gA = (long)(row0 + row) * D + k0 + (tid & 3) * 8;
                const long gB = (long)(col0 + row) * D + k0 + (tid & 3) * 8;
                const int lofs = rnd * 2048 + tid * 8;
                load_lds16(x_h + gA, sA + lofs);
                load_lds16(Wqk_h + gB, sBh + lofs);
                load_lds16(Wqk_l + gB, sBl + lofs);
            }
            __syncthreads();
            f16x8 a[4], b_h[4], b_l[4];
#pragma unroll
            for (int i = 0; i < 4; ++i)
                a[i] = *(const f16x8*)&sA[(wm + i * 16 + l16) * TK + (quad << 3)];
#pragma unroll
            for (int j = 0; j < 4; ++j) {
                b_h[j] = *(const f16x8*)&sBh[(wn + j * 16 + l16) * TK + (quad << 3)];
                b_l[j] = *(const f16x8*)&sBl[(wn + j * 16 + l16) * TK + (quad << 3)];
            }
#pragma unroll
            for (int i = 0; i < 4; ++i)
#pragma unroll
                for (int j = 0; j < 4; ++j) {
                    acc[i][j] = __builtin_amdgcn_mfma_f32_16x16x32_f16(a[i], b_h[j], acc[i][j], 0, 0, 0);
                    acc[i][j] = __builtin_amdgcn_mfma_f32_16x16x32_f16(a[i], b_l[j], acc[i][j], 0, 0, 0);
                }
            __syncthreads();
        }
        // epilogue: Q (hi only) or K (hi + lo)
        const bool isQ = col0 < D;
#pragma unroll
        for (int j = 0; j < 4; ++j) {
            const int col = col0 + wn + j * 16 + l16;
            const int cc = isQ ? col : col - D;
            const float bval = isQ ? bq[cc] : bk[cc];
#pragma unroll
            for (int i = 0; i < 4; ++i) {
                const int rb = row0 + wm + i * 16 + quad * 4;
#pragma unroll
                for (int r = 0; r < 4; ++r) {
                    const float v = acc[i][j][r] + bval;
                    const _Float16 h = (_Float16)v;
                    if (isQ) {
                        Q_h[(long)(rb + r) * D + cc] = h;
                    } else {
                        K_h[(long)(rb + r) * D + cc] = h;
                        K_l[(long)(rb + r) * D + cc] = (_Float16)(v - (float)h);
                    }
                }
            }
        }
    } else {
        for (int k0 = 0; k0 < D; k0 += TK) {
#pragma unroll
            for (int rnd = 0; rnd < 2; ++rnd) {
                const int row = rnd * 64 + (tid >> 2);
                const long gA = (long)(row0 + row) * D + k0 + (tid & 3) * 8;
                const long gB = (long)(col0 + row) * D + k0 + (tid & 3) * 8;
                const int lofs = rnd * 2048 + tid * 8;
                load_lds16(x_h + gA, sA + lofs);
                load_lds16(Wv_h + gB, sBh + lofs);
            }
            __syncthreads();
            f16x8 a[4], b[4];
#pragma unroll
            for (int i = 0; i < 4; ++i)
                a[i] = *(const f16x8*)&sA[(wm + i * 16 + l16) * TK + (quad << 3)];
#pragma unroll
            for (int j = 0; j < 4; ++j)
                b[j] = *(const f16x8*)&sBh[(wn + j * 16 + l16) * TK + (quad << 3)];
#pragma unroll
            for (int i = 0; i < 4; ++i)
#pragma unroll
                for (int j = 0; j < 4; ++j)
                    acc[i][j] = __builtin_amdgcn_mfma_f32_16x16x32_f16(a[i], b[j], acc[i][j], 0, 0, 0);
            __syncthreads();
        }
        // epilogue: transpose via XOR-swizzled LDS (aliases staging), 16B stores
        _Float16* sVt = smem;   // full 128x128 fp16 tile = 32 KB
#pragma unroll
        for (int j = 0; j < 4; ++j) {
            const int cl_ = wn + j * 16 + l16;
            const float bval = bv[col0 + cl_];
#pragma unroll
            for (int i = 0; i < 4; ++i) {
#pragma unroll
                for (int r = 0; r < 4; ++r) {
                    const int sl = wm + i * 16 + quad * 4 + r;
                    sVt[cl_ * TM + (sl ^ ((cl_ & 15) << 3))] = (_Float16)(acc[i][j][r] + bval);
                }
            }
        }
        __syncthreads();
        const int bb = row0 / SEQ;                 // tiles never cross batches
        const int sbase = row0 - bb * SEQ;
        for (int idx = tid; idx < TM * TM / 8; idx += 256) {
            const int cl_ = idx >> 4, s0 = (idx & 15) << 3;
            f16x8v v = *(const f16x8v*)&sVt[cl_ * TM + (s0 ^ ((cl_ & 15) << 3))];
            *(f16x8v*)&Vt[(long)bb * D * SEQ + (long)(col0 + cl_) * SEQ + sbase + s0] = v;
        }
    }
}

// ---------------------------------------------------------------------------
// gemm2: C = A @ B^T_layout (fp32 out). A fp16 [M][K] (hi only),
// B fp16 [N][K] hi (+ lo if BLO: 2-term accumulate). TM=128 x TNB, TK=32.
// MODE 1: causal packed triangular grid (x = live-tile id, TNB=64);
// MODE 2: PV, grid (x=rows heavy-first, y=cols), K bounded at (rt+1)*TM.
// ---------------------------------------------------------------------------
template<bool BLO, int MODE, int TNB>
__global__ __launch_bounds__(256)
void gemm2(const _Float16* __restrict__ Ah, long sA, int lda,
           const _Float16* __restrict__ Bh, const _Float16* __restrict__ Bl,
           long sB, int ldb,
           float* __restrict__ Cf, long sC, int ldc, int K)
{
    static_assert(MODE != 1 || TNB == 64, "packed causal decode assumes TNB=64");
    constexpr int NFJ = TNB / 32;
    constexpr int BRNDS = TNB / 64;

    int rt, ct;
    if (MODE == 1) {
        const int t = blockIdx.x;
        rt = (int)((sqrtf(4.0f * t + 1.0f) - 1.0f) * 0.5f);
        while (rt * (rt + 1) > t) --rt;
        while ((rt + 1) * (rt + 2) <= t) ++rt;
        ct = t - rt * (rt + 1);
    } else {
        rt = (gridDim.x - 1) - blockIdx.x;   // heavy rows first
        ct = blockIdx.y;
    }
    const int bz = blockIdx.z;

    const _Float16* gAh = Ah + (long)bz * sA;
    const _Float16* gBh = Bh + (long)bz * sB;
    const _Float16* gBl = BLO ? Bl + (long)bz * sB : nullptr;

    const int row0 = rt * TM, col0 = ct * TNB;
    const int k_end = (MODE == 2) ? min(K, (rt + 1) * TM) : K;

    __shared__ _Float16 sAh[TM * TK];
    __shared__ _Float16 sBh[TNB * TK];
    __shared__ _Float16 sBl[BLO ? TNB * TK : 8];

    const int tid = threadIdx.x;
    const int lane = tid & 63, wave = tid >> 6;
    const int l16 = lane & 15, quad = lane >> 4;
    const int wm = (wave >> 1) * 64, wn = (wave & 1) * (TNB / 2);

    f32x4 acc[4][NFJ] = {};

    for (int k0 = 0; k0 < k_end; k0 += TK) {
#pragma unroll
        for (int rnd = 0; rnd < 2; ++rnd) {
            const int row = rnd * 64 + (tid >> 2);
            const long gA = (long)(row0 + row) * lda + k0 + (tid & 3) * 8;
            load_lds16(gAh + gA, sAh + rnd * 2048 + tid * 8);
        }
#pragma unroll
        for (int rnd = 0; rnd < BRNDS; ++rnd) {
            const int row = rnd * 64 + (tid >> 2);
            const long gB = (long)(col0 + row) * ldb + k0 + (tid & 3) * 8;
            const int lofs = rnd * 2048 + tid * 8;
            load_lds16(gBh + gB, sBh + lofs);
            if (BLO) load_lds16(gBl + gB, sBl + lofs);
        }
        __syncthreads();

        f16x8 a[4], b_h[NFJ];
#pragma unroll
        for (int i = 0; i < 4; ++i)
            a[i] = *(const f16x8*)&sAh[(wm + i * 16 + l16) * TK + (quad << 3)];
#pragma unroll
        for (int j = 0; j < NFJ; ++j)
            b_h[j] = *(const f16x8*)&sBh[(wn + j * 16 + l16) * TK + (quad << 3)];

        if (BLO) {
            f16x8 b_l[NFJ];
#pragma unroll
            for (int j = 0; j < NFJ; ++j)
                b_l[j] = *(const f16x8*)&sBl[(wn + j * 16 + l16) * TK + (quad << 3)];
#pragma unroll
            for (int i = 0; i < 4; ++i)
#pragma unroll
                for (int j = 0; j < NFJ; ++j) {
                    acc[i][j] = __builtin_amdgcn_mfma_f32_16x16x32_f16(a[i], b_h[j], acc[i][j], 0, 0, 0);
                    acc[i][j] = __builtin_amdgcn_mfma_f32_16x16x32_f16(a[i], b_l[j], acc[i][j], 0, 0, 0);
                }
        } else {
#pragma unroll
            for (int i = 0; i < 4; ++i)
#pragma unroll
                for (int j = 0; j < NFJ; ++j)
                    acc[i][j] = __builtin_amdgcn_mfma_f32_16x16x32_f16(a[i], b_h[j], acc[i][j], 0, 0, 0);
        }
        __syncthreads();
    }

    float* cf = Cf + (long)bz * sC;
#pragma unroll
    for (int j = 0; j < NFJ; ++j) {
        const int col = col0 + wn + j * 16 + l16;
#pragma unroll
        for (int i = 0; i < 4; ++i) {
            const int rb = row0 + wm + i * 16 + quad * 4;
#pragma unroll
            for (int r = 0; r < 4; ++r)
                cf[(long)(rb + r) * ldc + col] = acc[i][j][r];
        }
    }
}

// ---------------------------------------------------------------------------
// softmax: causal, fp32 Sc row -> fp16 P row; loads only live 32B chunks,
// writes exactly the columns the PV GEMM will read (ceil((r+1)/128)*128).
// ---------------------------------------------------------------------------
__global__ __launch_bounds__(256)
void softmax_kernel(const float* __restrict__ Sc, _Float16* __restrict__ P, int seq)
{
    const int r = blockIdx.x, b = blockIdx.y;
    const float* row = Sc + ((long)b * seq + r) * seq;
    _Float16* prow = P + ((long)b * seq + r) * seq;
    const int tid = threadIdx.x;
    const int cmax = ((r >> 7) + 1) << 7;
    const int c0 = tid * 8;

    float v[8];
    f32x4 v0, v1;
    if (c0 <= r) {                 // chunk has at least one live column
        const f32x4* rp = (const f32x4*)row;
        v0 = rp[tid * 2];
        v1 = rp[tid * 2 + 1];
    } else {
        v0 = (f32x4)(-3.0e38f);
        v1 = (f32x4)(-3.0e38f);
    }
    float lmax = -3.0e38f;
#pragma unroll
    for (int k = 0; k < 4; ++k) {
        v[k]     = (c0 + k     <= r) ? v0[k] : -3.0e38f;
        v[k + 4] = (c0 + k + 4 <= r) ? v1[k] : -3.0e38f;
    }
#pragma unroll
    for (int k = 0; k < 8; ++k) lmax = fmaxf(lmax, v[k]);

    __shared__ float red[256];
    red[tid] = lmax; __syncthreads();
    for (int s = 128; s > 0; s >>= 1) {
        if (tid < s) red[tid] = fmaxf(red[tid], red[tid + s]);
        __syncthreads();
    }
    const float m = red[0];
    __syncthreads();

    float lsum = 0.0f;
#pragma unroll
    for (int k = 0; k < 8; ++k) {
        float e = (v[k] > -1.0e38f) ? __expf(v[k] - m) : 0.0f;
        v[k] = e;
        lsum += e;
    }
    red[tid] = lsum; __syncthreads();
    for (int s = 128; s > 0; s >>= 1) {
        if (tid < s) red[tid] += red[tid + s];
        __syncthreads();
    }
    const float inv = 1.0f / red[0];

    if (c0 < cmax) {
        f16x8v o;
#pragma unroll
        for (int k = 0; k < 8; ++k) o[k] = (_Float16)(v[k] * inv);
        ((f16x8v*)prow)[tid] = o;
    }
}

// ---------------------------------------------------------------------------
extern "C" void kernel_launch(void* const* d_in, const int* in_sizes, int n_in,
                              void* d_out, int out_size, void* d_ws, size_t ws_size,
                              hipStream_t stream)
{
    constexpr int B = 4, S = 2048, D = 1024;
    constexpr long MB = 1024 * 1024;
    const float* x  = (const float*)d_in[0];
    const float* Wq = (const float*)d_in[1];
    const float* bq = (const float*)d_in[2];
    const float* Wk = (const float*)d_in[3];
    const float* bk = (const float*)d_in[4];
    const float* Wv = (const float*)d_in[5];
    const float* bv = (const float*)d_in[6];
    float* out = (float*)d_out;

    // workspace layout (160 MB; Sc overlaps dead x/W regions)
    char* ws = (char*)d_ws;
    _Float16* x_h    = (_Float16*)(ws + 0);         // 16 MB
    _Float16* Wqkt_h = (_Float16*)(ws + 16 * MB);   // 4 MB [2048][1024]
    _Float16* Wqkt_l = (_Float16*)(ws + 20 * MB);   // 4 MB
    _Float16* Wvt_h  = (_Float16*)(ws + 24 * MB);   // 2 MB
    float*    Sc     = (float*)(ws + 0);            // 64 MB, after x/W dead
    _Float16* Q_h    = (_Float16*)(ws + 64 * MB);   // 16 MB [M][1024]
    _Float16* K_h    = (_Float16*)(ws + 80 * MB);   // 16 MB
    _Float16* K_l    = (_Float16*)(ws + 96 * MB);   // 16 MB
    _Float16* Vt     = (_Float16*)(ws + 112 * MB);  // 16 MB [B][D][S]
    _Float16* P      = (_Float16*)(ws + 128 * MB);  // 32 MB [B][S][S]

    const int M = B * S;  // 8192
    dim3 blk(256);

    // 1) convert x -> fp16 hi (A-side needs no lo)
    convert_h<<<(M * D / 4 + 255) / 256, blk, 0, stream>>>(x, x_h, (long)M * D / 4);
    // 2) all weight transposes in one dispatch (Wq,Wk hi+lo stacked; Wv hi)
    transpose_w3<<<dim3(D / 32, D / 32, 3), blk, 0, stream>>>(
        Wq, Wk, Wv, Wqkt_h, Wqkt_l, Wvt_h, D);

    // 3) fused projections: Q (ct 0..7), K (ct 8..15), V (ct 16..23)
    proj_fused<<<dim3(24, M / TM), blk, 0, stream>>>(
        x_h, Wqkt_h, Wqkt_l, Wvt_h, Q_h, K_h, K_l, Vt, bq, bk, bv);

    // 4) scores = Q_h @ (K_h + K_l)^T (2-term, packed triangular, TN=64) -> fp32
    const int ntiles = (S / TM) * (S / TM + 1);   // 272 live 128x64 tiles
    gemm2<true, 1, 64><<<dim3(ntiles, 1, B), blk, 0, stream>>>(
        Q_h, (long)S * D, D, K_h, K_l, (long)S * D, D,
        Sc, (long)S * S, S, D);

    // 5) causal softmax: fp32 Sc -> fp16 P
    softmax_kernel<<<dim3(S, B), blk, 0, stream>>>(Sc, P, S);

    // 6) out = P @ V (K-loop bounded at diagonal, heavy rows first, TN=64)
    gemm2<false, 2, 64><<<dim3(S / TM, D / 64, B), blk, 0, stream>>>(
        P, (long)S * S, S, Vt, nullptr, (long)D * S, S,
        out, (long)S * D, D, S);
}